// Round 20
// baseline (23.803 us; speedup 1.0000x reference)
//
#include <hip/hip_runtime.h>

#define CIN 16
#define COUT 32
#define NB 8
#define HW 4096
#define PPW 66                 // padded row width (64 + ring)
#define KF 160                 // features per pixel: 16ch * 10 (silu, T1..T8, zero)
#define NCH 20                 // 16B chunks per pixel
#define FROWS 6                // feature rows per block (4 output rows + halo)
#define PLANE 397              // padded chunk-plane stride in 16B units (6*66 + 1)

typedef short bf16x8 __attribute__((ext_vector_type(8)));
typedef float f32x16 __attribute__((ext_vector_type(16)));

__device__ inline unsigned short f2bf(float f) {
    unsigned u = __builtin_bit_cast(unsigned, f);
    u += 0x7FFFu + ((u >> 16) & 1u);            // RNE
    return (unsigned short)(u >> 16);
}
__device__ inline unsigned pk(float a, float b) {
    return (unsigned)f2bf(a) | ((unsigned)f2bf(b) << 16);
}

#define FEAT_SHORTS (NCH * PLANE * 8)      // 63520 shorts = 127040 B
#define LDS_BYTES (FEAT_SHORTS * 2)        // reduce area reuses feature LDS

// ---------- Tiny weight fold: 32x32-fragment-linear wfl (r9/r17/r19 mapping) ----------
// frag = shift*10 + st (st = K16 step);
//   wfl[frag*512 + lane*8 + e] = Wf[shift][o = lane&31][kel = st*16 + (lane>>5)*8 + e]
__global__ __launch_bounds__(512) void kan_wf(const float* __restrict__ w,
                                              const float* __restrict__ c,
                                              unsigned short* __restrict__ wfl) {
    const int t = blockIdx.x * 512 + threadIdx.x;   // 90*512 = 46080 exactly
    const int e    = t & 7;
    const int lane = (t >> 3) & 63;
    const int frag = t >> 9;              // 0..89
    const int shift = frag / 10;
    const int st    = frag % 10;
    const int o     = lane & 31;
    const int kel   = st * 16 + (lane >> 5) * 8 + e;
    const int i     = kel / 10, n = kel % 10;
    float val = 0.f;
    if (n != 9) {
        const float wv = w[(size_t)(i * COUT + o) * 9 + shift];
        val = (n == 0) ? wv : wv * c[((size_t)(i * COUT + o) * 9 + shift) * NB + (n - 1)];
    }
    wfl[t] = f2bf(val);
}

// ---------- Fused main: features -> LDS; 32x32x16 MFMA; 64px/wave; 4-way K-split ----------
// 256 blocks x 1024 thr = 1 block/CU, 16 waves. Block = 4 output rows of one image.
// Wave wv: row pg=wv>>2, K-lane par=wv&3 (st = par+4t, 3:3:2:2); covers all 64 px
// (two 32-px groups share each A-frag -> chip A-traffic 184->92 MB). Partial-acc
// reduce reuses the feature LDS after a barrier; par-0 wave sums and stores.
__global__ __launch_bounds__(1024, 4) void kan_main(const float* __restrict__ x,
                                                    const unsigned short* __restrict__ wfl,
                                                    float* __restrict__ out) {
    extern __shared__ __align__(16) unsigned short lds[];

    const int bid = blockIdx.x;
    const int b   = bid >> 4;            // image
    const int y0  = (bid & 15) * 4;      // first output row
    const int tid = threadIdx.x;

    // ---- P1: features (1584 items: 4 cg x 6 lr x 66 px) — r18/r19 verbatim ----
    for (int item = tid; item < 4 * FROWS * PPW; item += 1024) {
        const int cg  = item / (FROWS * PPW);
        const int rem = item - cg * (FROWS * PPW);
        const int lr  = rem / PPW;
        const int px  = rem - lr * PPW;
        const int iy  = y0 + lr - 1;

        unsigned rw[20];
        const bool valid = (iy >= 0) & (iy < 64) & (px >= 1) & (px <= 64);
        if (valid) {
            const int ix = px - 1;
#pragma unroll
            for (int j = 0; j < 4; ++j) {
                const int i = cg * 4 + j;
                const float v  = x[((size_t)(b * CIN + i)) * HW + iy * 64 + ix];
                const float p  = __expf(-v);
                const float p2 = p * p;
                const float s  = v * __builtin_amdgcn_rcpf(1.f + p);           // silu
                const float u  = (1.f - p2) * __builtin_amdgcn_rcpf(1.f + p2); // tanh
                const float u2 = 2.f * u;
                const float t1 = u;
                const float t2 = u2 * u - 1.f;
                const float t3 = u2 * t2 - t1;
                const float t4 = u2 * t3 - t2;
                const float t5 = u2 * t4 - t3;
                const float t6 = u2 * t5 - t4;
                const float t7 = u2 * t6 - t5;
                const float t8 = u2 * t7 - t6;
                rw[j * 5 + 0] = pk(s, t1);
                rw[j * 5 + 1] = pk(t2, t3);
                rw[j * 5 + 2] = pk(t4, t5);
                rw[j * 5 + 3] = pk(t6, t7);
                rw[j * 5 + 4] = (unsigned)f2bf(t8);   // hi half 0 (pad feature)
            }
        } else {
#pragma unroll
            for (int j = 0; j < 20; ++j) rw[j] = 0u;
        }
        const int base = lr * PPW + px;
#pragma unroll
        for (int q = 0; q < 5; ++q)
            *(uint4*)&lds[((cg * 5 + q) * PLANE + base) * 8] =
                make_uint4(rw[4 * q], rw[4 * q + 1], rw[4 * q + 2], rw[4 * q + 3]);
    }

    __syncthreads();

    // ---- P2: 32x32x16 MFMA, 64 px/wave, 4-way K-split ----
    const int l    = tid & 63;
    const int wv   = tid >> 6;           // 0..15
    const int pg   = wv >> 2;            // output row within block
    const int par  = wv & 3;             // K16-step class: st = par + 4t
    const int colp = l & 31;
    const int hi   = l >> 5;

    const unsigned short* abase = wfl + l * 8;   // lane-linear A from global (static addrs)

    f32x16 acc0, acc1;
#pragma unroll
    for (int r = 0; r < 16; ++r) { acc0[r] = 0.f; acc1[r] = 0.f; }

#pragma unroll
    for (int shift = 0; shift < 9; ++shift) {
        const int dy = shift / 3 - 1, dx = shift % 3 - 1;
        const int rbase = (pg + 1 + dy) * PPW + (colp + 1 + dx);
#pragma unroll
        for (int t = 0; t < 3; ++t) {
            const int st = par + 4 * t;
            if (st >= 10) break;         // wave-uniform (par 2,3 do 2 steps)
            const bf16x8 av = *(const bf16x8*)(abase + (shift * 10 + st) * 512);
            const unsigned short* bb = lds + ((st * 2 + hi) * PLANE + rbase) * 8;
            const bf16x8 bf0 = *(const bf16x8*)(bb);
            const bf16x8 bf1 = *(const bf16x8*)(bb + 32 * 8);   // px group 1 (+32 px)
            acc0 = __builtin_amdgcn_mfma_f32_32x32x16_bf16(av, bf0, acc0, 0, 0, 0);
            acc1 = __builtin_amdgcn_mfma_f32_32x32x16_bf16(av, bf1, acc1, 0, 0, 0);
        }
    }

    // ---- 4-way reduce: partials into (dead) feature LDS; par-0 sums + stores ----
    __syncthreads();                     // all feature reads complete
    float* red = (float*)lds;            // 24 planes x 4KB = 96KB <= 127KB
    if (par) {
        const int base = (((par - 1) * 4 + pg) * 2) * 1024;
#pragma unroll
        for (int r = 0; r < 16; ++r) {
            red[base + r * 64 + l]        = acc0[r];
            red[base + 1024 + r * 64 + l] = acc1[r];
        }
    }
    __syncthreads();
    if (par == 0) {
        float* op = out + (size_t)b * COUT * HW + (y0 + pg) * 64 + colp;
#pragma unroll
        for (int r = 0; r < 16; ++r) {
            float v0 = acc0[r], v1 = acc1[r];
#pragma unroll
            for (int p = 1; p < 4; ++p) {
                const int base = (((p - 1) * 4 + pg) * 2) * 1024;
                v0 += red[base + r * 64 + l];
                v1 += red[base + 1024 + r * 64 + l];
            }
            const int o = (r & 3) + 8 * (r >> 2) + 4 * hi;   // D row mapping [m74/m101]
            op[(size_t)o * HW]      = v0;
            op[(size_t)o * HW + 32] = v1;
        }
    }
}

extern "C" void kernel_launch(void* const* d_in, const int* in_sizes, int n_in,
                              void* d_out, int out_size, void* d_ws, size_t ws_size,
                              hipStream_t stream) {
    const float* x = (const float*)d_in[0];
    const float* w = (const float*)d_in[1];
    const float* c = (const float*)d_in[2];
    float* out = (float*)d_out;

    unsigned short* wfl = (unsigned short*)d_ws;     // 92160 B folded weights

    hipFuncSetAttribute((const void*)kan_main,
                        hipFuncAttributeMaxDynamicSharedMemorySize, LDS_BYTES);

    kan_wf<<<90, 512, 0, stream>>>(w, c, wfl);
    kan_main<<<256, 1024, LDS_BYTES, stream>>>(x, wfl, out);
}

// Round 21
// 21.320 us; speedup vs baseline: 1.1165x; 1.1165x over previous
//
#include <hip/hip_runtime.h>

#define CIN 16
#define COUT 32
#define NB 8
#define HW 4096
#define PPW 66                 // padded row width (64 + ring)
#define KF 160                 // features per pixel: 16ch * 10 (silu, T1..T8, zero)
#define NCH 20                 // 16B chunks per pixel
#define FROWS 6                // feature rows per block (4 output rows + halo)
#define PLANE 397              // padded chunk-plane stride in 16B units (6*66 + 1)

typedef short bf16x8 __attribute__((ext_vector_type(8)));
typedef float f32x16 __attribute__((ext_vector_type(16)));

__device__ inline unsigned short f2bf(float f) {
    unsigned u = __builtin_bit_cast(unsigned, f);
    u += 0x7FFFu + ((u >> 16) & 1u);            // RNE
    return (unsigned short)(u >> 16);
}
__device__ inline unsigned pk(float a, float b) {
    return (unsigned)f2bf(a) | ((unsigned)f2bf(b) << 16);
}

#define FEAT_SHORTS (NCH * PLANE * 8)          // 63520 shorts = 127040 B
#define LDS_BYTES (FEAT_SHORTS * 2 + 8 * 1024 * 4)   // + 32KB pair-reduce = 159808 B

// ---------- Tiny weight fold: 32x32-fragment-linear wfl (r9/r17 mapping) ----------
// frag = shift*10 + st (st = K16 step);
//   wfl[frag*512 + lane*8 + e] = Wf[shift][o = lane&31][kel = st*16 + (lane>>5)*8 + e]
__global__ __launch_bounds__(512) void kan_wf(const float* __restrict__ w,
                                              const float* __restrict__ c,
                                              unsigned short* __restrict__ wfl) {
    const int t = blockIdx.x * 512 + threadIdx.x;   // 90*512 = 46080 exactly
    const int e    = t & 7;
    const int lane = (t >> 3) & 63;
    const int frag = t >> 9;              // 0..89
    const int shift = frag / 10;
    const int st    = frag % 10;
    const int o     = lane & 31;
    const int kel   = st * 16 + (lane >> 5) * 8 + e;
    const int i     = kel / 10, n = kel % 10;
    float val = 0.f;
    if (n != 9) {
        const float wv = w[(size_t)(i * COUT + o) * 9 + shift];
        val = (n == 0) ? wv : wv * c[((size_t)(i * COUT + o) * 9 + shift) * NB + (n - 1)];
    }
    wfl[t] = f2bf(val);
}

// ---------- Fused main: features -> LDS, 32x32x16 MFMA, K-split wave pairs ----------
// 256 blocks x 1024 thr = 1 block/CU, 16 waves. Block = 4 output rows of one image.
// P1: 6 padded rows x 20 chunks -> LDS [c][PLANE] (padded stride: ~2-way banks). barrier.
// P2: 8 pairs; pair pg owns 32px x 32cout at (ry=pg>>1, x0=(pg&1)*32); wave parity
// does even/odd K16-steps (5 each, balanced). A global (1KB static loads, L2-hot),
// B ds_read_b128 (serves 32px). LDS pair-reduce, even wave stores.
__global__ __launch_bounds__(1024, 4) void kan_main(const float* __restrict__ x,
                                                    const unsigned short* __restrict__ wfl,
                                                    float* __restrict__ out) {
    extern __shared__ __align__(16) unsigned short lds[];

    const int bid = blockIdx.x;
    const int b   = bid >> 4;            // image
    const int y0  = (bid & 15) * 4;      // first output row
    const int tid = threadIdx.x;

    // ---- P1: features (1584 items: 4 cg x 6 lr x 66 px) ----
    for (int item = tid; item < 4 * FROWS * PPW; item += 1024) {
        const int cg  = item / (FROWS * PPW);
        const int rem = item - cg * (FROWS * PPW);
        const int lr  = rem / PPW;
        const int px  = rem - lr * PPW;
        const int iy  = y0 + lr - 1;

        unsigned rw[20];
        const bool valid = (iy >= 0) & (iy < 64) & (px >= 1) & (px <= 64);
        if (valid) {
            const int ix = px - 1;
#pragma unroll
            for (int j = 0; j < 4; ++j) {
                const int i = cg * 4 + j;
                const float v  = x[((size_t)(b * CIN + i)) * HW + iy * 64 + ix];
                const float p  = __expf(-v);
                const float p2 = p * p;
                const float s  = v * __builtin_amdgcn_rcpf(1.f + p);           // silu
                const float u  = (1.f - p2) * __builtin_amdgcn_rcpf(1.f + p2); // tanh
                const float u2 = 2.f * u;
                const float t1 = u;
                const float t2 = u2 * u - 1.f;
                const float t3 = u2 * t2 - t1;
                const float t4 = u2 * t3 - t2;
                const float t5 = u2 * t4 - t3;
                const float t6 = u2 * t5 - t4;
                const float t7 = u2 * t6 - t5;
                const float t8 = u2 * t7 - t6;
                rw[j * 5 + 0] = pk(s, t1);
                rw[j * 5 + 1] = pk(t2, t3);
                rw[j * 5 + 2] = pk(t4, t5);
                rw[j * 5 + 3] = pk(t6, t7);
                rw[j * 5 + 4] = (unsigned)f2bf(t8);   // hi half 0 (pad feature)
            }
        } else {
#pragma unroll
            for (int j = 0; j < 20; ++j) rw[j] = 0u;
        }
        const int base = lr * PPW + px;
#pragma unroll
        for (int q = 0; q < 5; ++q)
            *(uint4*)&lds[((cg * 5 + q) * PLANE + base) * 8] =
                make_uint4(rw[4 * q], rw[4 * q + 1], rw[4 * q + 2], rw[4 * q + 3]);
    }

    __syncthreads();

    // ---- P2: 32x32x16 MFMA, K-parity split ----
    const int l    = tid & 63;
    const int wv   = tid >> 6;           // 0..15
    const int pg   = wv >> 1;            // pair 0..7
    const int par  = wv & 1;             // K16-step parity
    const int ry   = pg >> 1;            // row within block
    const int x0   = (pg & 1) * 32;
    const int colp = l & 31;
    const int hi   = l >> 5;

    const unsigned short* abase = wfl + l * 8;   // lane-linear A from global (static addrs)

    f32x16 acc;
#pragma unroll
    for (int r = 0; r < 16; ++r) acc[r] = 0.f;

#pragma unroll
    for (int shift = 0; shift < 9; ++shift) {
        const int dy = shift / 3 - 1, dx = shift % 3 - 1;
        const int base = (ry + 1 + dy) * PPW + (x0 + colp + 1 + dx);
        const unsigned short* aq = abase + (shift * 10 + par) * 512;
        // K16-step st = 2t + par; B chunk = st*2 + hi = 4t + 2*par + hi
        const unsigned short* bb = lds + ((2 * par + hi) * PLANE + base) * 8;
#pragma unroll
        for (int t = 0; t < 5; ++t) {
            const bf16x8 bf = *(const bf16x8*)(bb + (size_t)(4 * t) * PLANE * 8);
            const bf16x8 av = *(const bf16x8*)(aq + (2 * t) * 512);
            acc = __builtin_amdgcn_mfma_f32_32x32x16_bf16(av, bf, acc, 0, 0, 0);
        }
    }

    // ---- pair reduce (32KB area after features) ----
    float* red = (float*)(lds + FEAT_SHORTS);
    if (par) {
#pragma unroll
        for (int r = 0; r < 16; ++r) red[pg * 1024 + r * 64 + l] = acc[r];
    }
    __syncthreads();
    if (!par) {
        float* op = out + (size_t)b * COUT * HW + (y0 + ry) * 64 + x0 + colp;
#pragma unroll
        for (int r = 0; r < 16; ++r) {
            const float v = acc[r] + red[pg * 1024 + r * 64 + l];
            const int o = (r & 3) + 8 * (r >> 2) + 4 * hi;   // D row mapping [m74/m101, r9/r17-verified]
            op[(size_t)o * HW] = v;
        }
    }
}

extern "C" void kernel_launch(void* const* d_in, const int* in_sizes, int n_in,
                              void* d_out, int out_size, void* d_ws, size_t ws_size,
                              hipStream_t stream) {
    const float* x = (const float*)d_in[0];
    const float* w = (const float*)d_in[1];
    const float* c = (const float*)d_in[2];
    float* out = (float*)d_out;

    unsigned short* wfl = (unsigned short*)d_ws;     // 92160 B folded weights

    hipFuncSetAttribute((const void*)kan_main,
                        hipFuncAttributeMaxDynamicSharedMemorySize, LDS_BYTES);

    kan_wf<<<90, 512, 0, stream>>>(w, c, wfl);
    kan_main<<<256, 1024, LDS_BYTES, stream>>>(x, wfl, out);
}